// Round 5
// baseline (339.533 us; speedup 1.0000x reference)
//
#include <hip/hip_runtime.h>
#include <stdint.h>

// B=2, L=2048, DM=1024, H=16, D=64
// ws layout (50 MB):
//   xb    bf16[4096][1024]  x converted            (reused as arb after proj GEMM)
//   wcatT bf16[4096][1024]  [wq*0.125*log2e|wk|wqr|wkr]^T (reused as krT)
//   qcat  bf16[4096][4096]  q|k|qr|kr col blocks
//   wotT  bf16[1024][1024]  wo^T
// krT layout: [b*16+h][64 d][2048 l]

typedef __attribute__((ext_vector_type(4))) float floatx4;
typedef __attribute__((ext_vector_type(8))) short shortx8;
typedef __attribute__((ext_vector_type(4))) short shortx4;

__device__ __forceinline__ unsigned short f2bf(float f) {
    unsigned u = __float_as_uint(f);
    u += 0x7fffu + ((u >> 16) & 1u);   // RNE
    return (unsigned short)(u >> 16);
}
__device__ __forceinline__ float bf2f(unsigned short s) {
    return __uint_as_float(((unsigned)s) << 16);
}
__device__ __forceinline__ float exp2fast(float x) {
#if __has_builtin(__builtin_amdgcn_exp2f)
    return __builtin_amdgcn_exp2f(x);
#else
    return __expf(x * 0.69314718056f);
#endif
}
// PV MFMA: D += A(4 bf16, k=quad*4+i) * B(4 bf16, k=quad*4+i)
__device__ __forceinline__ floatx4 mfma16(shortx4 a, shortx4 b, floatx4 c) {
#if __has_builtin(__builtin_amdgcn_mfma_f32_16x16x16bf16_1k)
    return __builtin_amdgcn_mfma_f32_16x16x16bf16_1k(a, b, c, 0, 0, 0);
#else
    // zero-pad into 16x16x32: k = quad*8+i, nonzero at i<4 for BOTH operands ->
    // identical k->key mapping (key = quad*4+i), zeros elsewhere contribute 0.
    shortx8 a8 = {a[0], a[1], a[2], a[3], 0, 0, 0, 0};
    shortx8 b8 = {b[0], b[1], b[2], b[3], 0, 0, 0, 0};
    return __builtin_amdgcn_mfma_f32_16x16x32_bf16(a8, b8, c, 0, 0, 0);
#endif
}
// async global->LDS, 16B/lane; lds dest = wave-uniform base + lane*16
__device__ __forceinline__ void gll16(const void* g, void* l) {
    __builtin_amdgcn_global_load_lds(
        (const __attribute__((address_space(1))) unsigned int*)g,
        (__attribute__((address_space(3))) unsigned int*)l, 16, 0, 0);
}

// ---------- x -> bf16 (coalesced) ----------
__global__ void k_cvt_x(const float* __restrict__ x, unsigned short* __restrict__ xb) {
    int i = (blockIdx.x * 256 + threadIdx.x) * 4;
    float4 v = *(const float4*)(x + i);
    ushort4 o;
    o.x = f2bf(v.x); o.y = f2bf(v.y); o.z = f2bf(v.z); o.w = f2bf(v.w);
    *(ushort4*)(xb + i) = o;
}

// ---------- all 5 weights: fp32 [k][n] -> bf16 [n][k], LDS-tiled; z selects W ----------
__global__ __launch_bounds__(256) void k_cvt_w5(const float* __restrict__ wq,
                                                const float* __restrict__ wk,
                                                const float* __restrict__ wqr,
                                                const float* __restrict__ wkr,
                                                const float* __restrict__ wo,
                                                unsigned short* __restrict__ wcatT,
                                                unsigned short* __restrict__ wotT) {
    __shared__ unsigned short Tl[64 * 65];
    const int t = threadIdx.x;
    const int kt = blockIdx.x * 64, nt = blockIdx.y * 64;
    const int z = blockIdx.z;
    const float* W = (z == 0) ? wq : (z == 1) ? wk : (z == 2) ? wqr : (z == 3) ? wkr : wo;
    unsigned short* outT = (z < 4) ? (wcatT + (size_t)z * 1024 * 1024) : wotT;
    // fold SDPA scale AND log2(e) into wq: scores in log2 domain, p = 2^z
    const float scale = (z == 0) ? 0.18033688f : 1.0f;   // 0.125 * 1.44269504
    {
        const int kl = t >> 3, nc = (t & 7) * 8;
        const float* src = W + (size_t)(kt + kl) * 1024 + nt + nc;
        float a[8], b[8];
        *(float4*)(a)     = *(const float4*)(src);
        *(float4*)(a + 4) = *(const float4*)(src + 4);
        *(float4*)(b)     = *(const float4*)(src + 32 * 1024);
        *(float4*)(b + 4) = *(const float4*)(src + 32 * 1024 + 4);
#pragma unroll
        for (int i = 0; i < 8; ++i) {
            Tl[kl * 65 + nc + i]        = f2bf(a[i] * scale);
            Tl[(kl + 32) * 65 + nc + i] = f2bf(b[i] * scale);
        }
    }
    __syncthreads();
    {
        const int n = t >> 2, kc = (t & 3) * 16;
        shortx8 o0, o1;
#pragma unroll
        for (int i = 0; i < 8; ++i) {
            o0[i] = (short)Tl[(kc + i) * 65 + n];
            o1[i] = (short)Tl[(kc + 8 + i) * 65 + n];
        }
        unsigned short* dst = outT + (size_t)(nt + n) * 1024 + kt + kc;
        *(shortx8*)(dst)     = o0;
        *(shortx8*)(dst + 8) = o1;
    }
}

// ---------- KR (qcat cols 3072..4095, [l][h*64+d]) -> krT [bh][d][l] ----------
__global__ __launch_bounds__(256) void k_trans(const unsigned short* __restrict__ qcat,
                                               unsigned short* __restrict__ krT) {
    __shared__ unsigned short Tl[64 * 65];
    const int t = threadIdx.x;
    const int mt = blockIdx.x * 64;
    const int bh = blockIdx.y;
    const int b = bh >> 4, h = bh & 15;
    {
        const int ml = t >> 3, dc = (t & 7) * 8;
        const unsigned short* src =
            qcat + ((size_t)b * 2048 + mt + ml) * 4096 + 3072 + h * 64 + dc;
        shortx8 v0 = *(const shortx8*)(src);
        shortx8 v1 = *(const shortx8*)(src + (size_t)32 * 4096);
#pragma unroll
        for (int i = 0; i < 8; ++i) {
            Tl[ml * 65 + dc + i]        = (unsigned short)v0[i];
            Tl[(ml + 32) * 65 + dc + i] = (unsigned short)v1[i];
        }
    }
    __syncthreads();
    {
        const int d = t >> 2, mc = (t & 3) * 16;
        shortx8 o0, o1;
#pragma unroll
        for (int i = 0; i < 8; ++i) {
            o0[i] = (short)Tl[(mc + i) * 65 + d];
            o1[i] = (short)Tl[(mc + 8 + i) * 65 + d];
        }
        unsigned short* dst = krT + ((size_t)bh * 64 + d) * 2048 + mt + mc;
        *(shortx8*)(dst)     = o0;
        *(shortx8*)(dst + 8) = o1;
    }
}

// ---------- GEMM 128x128x(BK=32), double-buffered LDS, 1 barrier/iter ----------
__global__ __launch_bounds__(256) void k_gemm_bt(const unsigned short* __restrict__ A,
                                                 const unsigned short* __restrict__ Bt,
                                                 unsigned short* __restrict__ C,
                                                 int N, int K) {
    __shared__ alignas(16) unsigned short As[2][128 * 32];
    __shared__ alignas(16) unsigned short Bs[2][128 * 32];
    const int t = threadIdx.x;
    const int lane = t & 63, wv = t >> 6;
    const int ln = lane & 15, quad = lane >> 4;
    const int wm = wv >> 1, wn = wv & 1;
    const int bm = blockIdx.y * 128, bn = blockIdx.x * 128;

    floatx4 acc[4][4] = {};

    const unsigned short* ga0 = A + (size_t)(bm + (t >> 2)) * K + (t & 3) * 8;
    const unsigned short* ga1 = ga0 + (size_t)64 * K;
    const unsigned short* gb0 = Bt + (size_t)(bn + (t >> 2)) * K + (t & 3) * 8;
    const unsigned short* gb1 = gb0 + (size_t)64 * K;

    // prologue: stage k0=0 into buffer 0
    gll16(ga0, &As[0][wv * 512]);
    gll16(ga1, &As[0][2048 + wv * 512]);
    gll16(gb0, &Bs[0][wv * 512]);
    gll16(gb1, &Bs[0][2048 + wv * 512]);

    int cur = 0;
    for (int k0 = 0; k0 < K; k0 += 32, cur ^= 1) {
        __syncthreads();   // drains prefetch (landed during prev compute)
        const int nk = k0 + 32;
        if (nk < K) {      // prefetch next tile into alternate buffer
            gll16(ga0 + nk, &As[cur ^ 1][wv * 512]);
            gll16(ga1 + nk, &As[cur ^ 1][2048 + wv * 512]);
            gll16(gb0 + nk, &Bs[cur ^ 1][wv * 512]);
            gll16(gb1 + nk, &Bs[cur ^ 1][2048 + wv * 512]);
        }
        shortx8 af[4], bfr[4];
#pragma unroll
        for (int i = 0; i < 4; ++i)
            af[i] = *(const shortx8*)(&As[cur][(wm * 64 + i * 16 + ln) * 32 + quad * 8]);
#pragma unroll
        for (int j = 0; j < 4; ++j)
            bfr[j] = *(const shortx8*)(&Bs[cur][(wn * 64 + j * 16 + ln) * 32 + quad * 8]);
#pragma unroll
        for (int i = 0; i < 4; ++i)
#pragma unroll
            for (int j = 0; j < 4; ++j)
                acc[i][j] = __builtin_amdgcn_mfma_f32_16x16x32_bf16(af[i], bfr[j], acc[i][j], 0, 0, 0);
    }

#pragma unroll
    for (int i = 0; i < 4; ++i)
#pragma unroll
        for (int j = 0; j < 4; ++j)
#pragma unroll
            for (int r = 0; r < 4; ++r) {
                int row = bm + wm * 64 + i * 16 + quad * 4 + r;
                int col = bn + wn * 64 + j * 16 + ln;
                C[(size_t)row * N + col] = f2bf(acc[i][j][r]);
            }
}

// ---------- GEMM 128x64 tiles (output proj), double-buffered ----------
__global__ __launch_bounds__(256) void k_gemm_n64(const unsigned short* __restrict__ A,
                                                  const unsigned short* __restrict__ Bt,
                                                  float* __restrict__ C,
                                                  int N, int K) {
    __shared__ alignas(16) unsigned short As[2][128 * 32];
    __shared__ alignas(16) unsigned short Bs[2][64 * 32];
    const int t = threadIdx.x;
    const int lane = t & 63, wv = t >> 6;
    const int ln = lane & 15, quad = lane >> 4;
    const int bm = blockIdx.y * 128, bn = blockIdx.x * 64;

    floatx4 acc[2][4] = {};

    const unsigned short* ga0 = A + (size_t)(bm + (t >> 2)) * K + (t & 3) * 8;
    const unsigned short* ga1 = ga0 + (size_t)64 * K;
    const unsigned short* gb0 = Bt + (size_t)(bn + (t >> 2)) * K + (t & 3) * 8;

    gll16(ga0, &As[0][wv * 512]);
    gll16(ga1, &As[0][2048 + wv * 512]);
    gll16(gb0, &Bs[0][wv * 512]);

    int cur = 0;
    for (int k0 = 0; k0 < K; k0 += 32, cur ^= 1) {
        __syncthreads();
        const int nk = k0 + 32;
        if (nk < K) {
            gll16(ga0 + nk, &As[cur ^ 1][wv * 512]);
            gll16(ga1 + nk, &As[cur ^ 1][2048 + wv * 512]);
            gll16(gb0 + nk, &Bs[cur ^ 1][wv * 512]);
        }
        shortx8 af[2], bfr[4];
#pragma unroll
        for (int i = 0; i < 2; ++i)
            af[i] = *(const shortx8*)(&As[cur][(wv * 32 + i * 16 + ln) * 32 + quad * 8]);
#pragma unroll
        for (int j = 0; j < 4; ++j)
            bfr[j] = *(const shortx8*)(&Bs[cur][(j * 16 + ln) * 32 + quad * 8]);
#pragma unroll
        for (int i = 0; i < 2; ++i)
#pragma unroll
            for (int j = 0; j < 4; ++j)
                acc[i][j] = __builtin_amdgcn_mfma_f32_16x16x32_bf16(af[i], bfr[j], acc[i][j], 0, 0, 0);
    }

#pragma unroll
    for (int i = 0; i < 2; ++i)
#pragma unroll
        for (int j = 0; j < 4; ++j)
#pragma unroll
            for (int r = 0; r < 4; ++r) {
                int row = bm + wv * 32 + i * 16 + quad * 4 + r;
                int col = bn + j * 16 + ln;
                C[(size_t)row * N + col] = acc[i][j][r];
            }
}

// ---------- fused causal attention + Hadamard: barrier-free, zero-LDS ----------
// Q-tile 128 rows, K-tile 64. grid (16 qt-swizzled, 32 bh), 4 waves, no __shared__.
// Wave w, c in {0,1}: owns q = l0 + c*64 + w*16 + ln.
// S^T = K·Q^T via 16x16x32 (A=K frags from global, B=Q regs).
// P stays in registers: S^T C-layout (keys quad*4+r) == 16x16x16 B-layout (k=quad*4+i).
// PV: O^T += KR^T·P^T via mfma16 (A=KR frags from global).
__global__ __launch_bounds__(256, 2) void k_attn(const unsigned short* __restrict__ qcat,
                                                 const unsigned short* __restrict__ krT,
                                                 unsigned short* __restrict__ ar) {
    const int t = threadIdx.x;
    const int lane = t & 63, w = t >> 6;
    const int ln = lane & 15, quad = lane >> 4;
    const int bh = blockIdx.y;
    const int b = bh >> 4, h = bh & 15;
    const int qx = blockIdx.x;
    const int qt = (qx & 1) ? 15 - (qx >> 1) : (qx >> 1);  // pairwise load balance
    const int l0 = qt * 128;
    const size_t baserow = (size_t)b * 2048;
    const int ktmax = 2 * qt + 1;

    // Q B-frags (loop-invariant): col q, k(d) = quad*8+i (+32*ks)
    shortx8 aq[2][2];
    int qrow[2];
#pragma unroll
    for (int c = 0; c < 2; ++c) {
        qrow[c] = l0 + c * 64 + w * 16 + ln;
        const unsigned short* qp = qcat + (baserow + qrow[c]) * 4096 + h * 64 + quad * 8;
        aq[c][0] = *(const shortx8*)(qp);
        aq[c][1] = *(const shortx8*)(qp + 32);
    }

    floatx4 acc_o[2][4] = {};   // [c][jd]; lane: col q, rows d = jd*16+quad*4+r
    float lsum[2] = {0.f, 0.f};

    // lane-based global bases (wave-independent rows -> L1-shared across waves)
    const unsigned short* gK = qcat + (baserow + ln) * 4096 + 1024 + h * 64 + quad * 8;
    const unsigned short* gR = krT + ((size_t)bh * 64 + ln) * 2048 + quad * 4;

    shortx8 kfA[4][2], kfB[4][2];

    auto loadK = [&](int kt, shortx8 (&dst)[4][2]) {
#pragma unroll
        for (int jk = 0; jk < 4; ++jk)
#pragma unroll
            for (int ks = 0; ks < 2; ++ks)
                dst[jk][ks] =
                    *(const shortx8*)(gK + (size_t)(kt * 64 + jk * 16) * 4096 + ks * 32);
    };

    auto body = [&](int kt, shortx8 (&kfu)[4][2], shortx8 (&kfp)[4][2]) {
        // register prefetch of K(kt+1) — clamped (last iter reloads kt, harmless)
        const int ktn = (kt < ktmax) ? kt + 1 : ktmax;
        loadK(ktn, kfp);
        // KR A-frags for this tile (consumed after S^T phase)
        shortx4 krf[4][4];
#pragma unroll
        for (int jd = 0; jd < 4; ++jd)
#pragma unroll
            for (int jk = 0; jk < 4; ++jk)
                krf[jd][jk] =
                    *(const shortx4*)(gR + (size_t)jd * 16 * 2048 + kt * 64 + jk * 16);

        // diagonal-or-beyond tiles need masking; global key vs global q
        const bool msk[2] = {kt >= 2 * qt, kt == ktmax};

        shortx4 pk[2][4];
#pragma unroll
        for (int jk = 0; jk < 4; ++jk) {
            const int keyb = kt * 64 + jk * 16 + quad * 4;   // global key index (+r)
#pragma unroll
            for (int c = 0; c < 2; ++c) {
                floatx4 z = {0.f, 0.f, 0.f, 0.f};
                z = __builtin_amdgcn_mfma_f32_16x16x32_bf16(kfu[jk][0], aq[c][0], z, 0, 0, 0);
                z = __builtin_amdgcn_mfma_f32_16x16x32_bf16(kfu[jk][1], aq[c][1], z, 0, 0, 0);
#pragma unroll
                for (int r = 0; r < 4; ++r) {
                    float e = exp2fast(z[r]);
                    e = (msk[c] && (keyb + r > qrow[c])) ? 0.f : e;   // causal: key > q
                    lsum[c] += e;
                    pk[c][jk][r] = (short)f2bf(e);
                }
            }
        }

        // PV: P^T already in B-layout for 16x16x16
#pragma unroll
        for (int jk = 0; jk < 4; ++jk)
#pragma unroll
            for (int jd = 0; jd < 4; ++jd) {
                acc_o[0][jd] = mfma16(krf[jd][jk], pk[0][jk], acc_o[0][jd]);
                acc_o[1][jd] = mfma16(krf[jd][jk], pk[1][jk], acc_o[1][jd]);
            }
    };

    loadK(0, kfA);
    for (int kt = 0; kt < ktmax; kt += 2) {   // ktmax odd -> (ktmax+1) iters, exact pairs
        body(kt, kfA, kfB);
        body(kt + 1, kfB, kfA);
    }

    // epilogue: reduce lsum over quads, /sum, Hadamard qr, packed b64 stores
#pragma unroll
    for (int c = 0; c < 2; ++c) {
        float s = lsum[c];
        s += __shfl_xor(s, 16);
        s += __shfl_xor(s, 32);
        const float inv = 1.0f / s;
        const int q = qrow[c];
        const unsigned short* qr = qcat + (baserow + q) * 4096 + 2048 + h * 64;
        unsigned short* arow = ar + (baserow + q) * 1024 + h * 64;
#pragma unroll
        for (int jd = 0; jd < 4; ++jd) {
            const int d0 = jd * 16 + quad * 4;
            shortx4 qv = *(const shortx4*)(qr + d0);
            shortx4 o;
#pragma unroll
            for (int r = 0; r < 4; ++r)
                o[r] = (short)f2bf(acc_o[c][jd][r] * inv * bf2f((unsigned short)qv[r]));
            *(shortx4*)(arow + d0) = o;
        }
    }
}

extern "C" void kernel_launch(void* const* d_in, const int* in_sizes, int n_in,
                              void* d_out, int out_size, void* d_ws, size_t ws_size,
                              hipStream_t stream) {
    const float* x   = (const float*)d_in[0];
    const float* wq  = (const float*)d_in[1];
    const float* wk  = (const float*)d_in[2];
    const float* wqr = (const float*)d_in[3];
    const float* wkr = (const float*)d_in[4];
    const float* wo  = (const float*)d_in[5];
    float* out = (float*)d_out;

    unsigned short* xb    = (unsigned short*)d_ws;
    unsigned short* wcatT = xb + (size_t)4096 * 1024;
    unsigned short* qcat  = wcatT + (size_t)4096 * 1024;
    unsigned short* wotT  = qcat + (size_t)4096 * 4096;
    unsigned short* krT   = wcatT;   // wcatT dead after proj GEMM
    unsigned short* arb   = xb;      // xb dead after proj GEMM

    k_cvt_x<<<4096, 256, 0, stream>>>(x, xb);
    k_cvt_w5<<<dim3(16, 16, 5), 256, 0, stream>>>(wq, wk, wqr, wkr, wo, wcatT, wotT);
    k_gemm_bt<<<dim3(32, 32), 256, 0, stream>>>(xb, wcatT, qcat, 4096, 1024);
    k_trans<<<dim3(32, 32), 256, 0, stream>>>(qcat, krT);
    k_attn<<<dim3(16, 32), 256, 0, stream>>>(qcat, krT, arb);
    k_gemm_n64<<<dim3(16, 32), 256, 0, stream>>>(arb, wotT, out, 1024, 1024);
}

// Round 6
// 215.856 us; speedup vs baseline: 1.5730x; 1.5730x over previous
//
#include <hip/hip_runtime.h>
#include <stdint.h>

// B=2, L=2048, DM=1024, H=16, D=64
// ws layout (50 MB):
//   xb    bf16[4096][1024]  x converted            (reused as arb after proj GEMM)
//   wcatT bf16[4096][1024]  [wq*0.125*log2e|wk|wqr|wkr]^T (reused as krT)
//   qcat  bf16[4096][4096]  q|k|qr|kr col blocks
//   wotT  bf16[1024][1024]  wo^T
// krT layout: [b*16+h][64 d][2048 l]

typedef __attribute__((ext_vector_type(4))) float floatx4;
typedef __attribute__((ext_vector_type(8))) short shortx8;
typedef __attribute__((ext_vector_type(4))) short shortx4;

__device__ __forceinline__ unsigned short f2bf(float f) {
    unsigned u = __float_as_uint(f);
    u += 0x7fffu + ((u >> 16) & 1u);   // RNE
    return (unsigned short)(u >> 16);
}
__device__ __forceinline__ float bf2f(unsigned short s) {
    return __uint_as_float(((unsigned)s) << 16);
}
__device__ __forceinline__ float exp2fast(float x) {
#if __has_builtin(__builtin_amdgcn_exp2f)
    return __builtin_amdgcn_exp2f(x);
#else
    return __expf(x * 0.69314718056f);
#endif
}
// PV MFMA: D += A(4 bf16, k=quad*4+i) * B(4 bf16, k=quad*4+i)
__device__ __forceinline__ floatx4 mfma16(shortx4 a, shortx4 b, floatx4 c) {
#if __has_builtin(__builtin_amdgcn_mfma_f32_16x16x16bf16_1k)
    return __builtin_amdgcn_mfma_f32_16x16x16bf16_1k(a, b, c, 0, 0, 0);
#else
    shortx8 a8 = {a[0], a[1], a[2], a[3], 0, 0, 0, 0};
    shortx8 b8 = {b[0], b[1], b[2], b[3], 0, 0, 0, 0};
    return __builtin_amdgcn_mfma_f32_16x16x32_bf16(a8, b8, c, 0, 0, 0);
#endif
}
// async global->LDS, 16B/lane; lds dest = wave-uniform base + lane*16
__device__ __forceinline__ void gll16(const void* g, void* l) {
    __builtin_amdgcn_global_load_lds(
        (const __attribute__((address_space(1))) unsigned int*)g,
        (__attribute__((address_space(3))) unsigned int*)l, 16, 0, 0);
}

// ---------- x -> bf16 (coalesced) ----------
__global__ void k_cvt_x(const float* __restrict__ x, unsigned short* __restrict__ xb) {
    int i = (blockIdx.x * 256 + threadIdx.x) * 4;
    float4 v = *(const float4*)(x + i);
    ushort4 o;
    o.x = f2bf(v.x); o.y = f2bf(v.y); o.z = f2bf(v.z); o.w = f2bf(v.w);
    *(ushort4*)(xb + i) = o;
}

// ---------- all 5 weights: fp32 [k][n] -> bf16 [n][k], LDS-tiled; z selects W ----------
__global__ __launch_bounds__(256) void k_cvt_w5(const float* __restrict__ wq,
                                                const float* __restrict__ wk,
                                                const float* __restrict__ wqr,
                                                const float* __restrict__ wkr,
                                                const float* __restrict__ wo,
                                                unsigned short* __restrict__ wcatT,
                                                unsigned short* __restrict__ wotT) {
    __shared__ unsigned short Tl[64 * 65];
    const int t = threadIdx.x;
    const int kt = blockIdx.x * 64, nt = blockIdx.y * 64;
    const int z = blockIdx.z;
    const float* W = (z == 0) ? wq : (z == 1) ? wk : (z == 2) ? wqr : (z == 3) ? wkr : wo;
    unsigned short* outT = (z < 4) ? (wcatT + (size_t)z * 1024 * 1024) : wotT;
    // fold SDPA scale AND log2(e) into wq: scores in log2 domain, p = 2^z
    const float scale = (z == 0) ? 0.18033688f : 1.0f;   // 0.125 * 1.44269504
    {
        const int kl = t >> 3, nc = (t & 7) * 8;
        const float* src = W + (size_t)(kt + kl) * 1024 + nt + nc;
        float a[8], b[8];
        *(float4*)(a)     = *(const float4*)(src);
        *(float4*)(a + 4) = *(const float4*)(src + 4);
        *(float4*)(b)     = *(const float4*)(src + 32 * 1024);
        *(float4*)(b + 4) = *(const float4*)(src + 32 * 1024 + 4);
#pragma unroll
        for (int i = 0; i < 8; ++i) {
            Tl[kl * 65 + nc + i]        = f2bf(a[i] * scale);
            Tl[(kl + 32) * 65 + nc + i] = f2bf(b[i] * scale);
        }
    }
    __syncthreads();
    {
        const int n = t >> 2, kc = (t & 3) * 16;
        shortx8 o0, o1;
#pragma unroll
        for (int i = 0; i < 8; ++i) {
            o0[i] = (short)Tl[(kc + i) * 65 + n];
            o1[i] = (short)Tl[(kc + 8 + i) * 65 + n];
        }
        unsigned short* dst = outT + (size_t)(nt + n) * 1024 + kt + kc;
        *(shortx8*)(dst)     = o0;
        *(shortx8*)(dst + 8) = o1;
    }
}

// ---------- KR (qcat cols 3072..4095, [l][h*64+d]) -> krT [bh][d][l] ----------
__global__ __launch_bounds__(256) void k_trans(const unsigned short* __restrict__ qcat,
                                               unsigned short* __restrict__ krT) {
    __shared__ unsigned short Tl[64 * 65];
    const int t = threadIdx.x;
    const int mt = blockIdx.x * 64;
    const int bh = blockIdx.y;
    const int b = bh >> 4, h = bh & 15;
    {
        const int ml = t >> 3, dc = (t & 7) * 8;
        const unsigned short* src =
            qcat + ((size_t)b * 2048 + mt + ml) * 4096 + 3072 + h * 64 + dc;
        shortx8 v0 = *(const shortx8*)(src);
        shortx8 v1 = *(const shortx8*)(src + (size_t)32 * 4096);
#pragma unroll
        for (int i = 0; i < 8; ++i) {
            Tl[ml * 65 + dc + i]        = (unsigned short)v0[i];
            Tl[(ml + 32) * 65 + dc + i] = (unsigned short)v1[i];
        }
    }
    __syncthreads();
    {
        const int d = t >> 2, mc = (t & 3) * 16;
        shortx8 o0, o1;
#pragma unroll
        for (int i = 0; i < 8; ++i) {
            o0[i] = (short)Tl[(mc + i) * 65 + d];
            o1[i] = (short)Tl[(mc + 8 + i) * 65 + d];
        }
        unsigned short* dst = krT + ((size_t)bh * 64 + d) * 2048 + mt + mc;
        *(shortx8*)(dst)     = o0;
        *(shortx8*)(dst + 8) = o1;
    }
}

// ---------- GEMM 128x128x(BK=32), dbuf gll16, XOR-swizzled chunks ----------
// LDS tile [row][4 chunks of 8 shorts]; chunk slot c' holds global chunk c'^(row&3).
// Frag read (row=...*16+ln, chunk=quad... wait quad in 0..3? chunk cm=quad&3 per 8-short
// group; reads use ((cm)^(ln&3)). 2-way banks instead of 8-way.
__global__ __launch_bounds__(256) void k_gemm_bt(const unsigned short* __restrict__ A,
                                                 const unsigned short* __restrict__ Bt,
                                                 unsigned short* __restrict__ C,
                                                 int N, int K) {
    __shared__ alignas(16) unsigned short As[2][128 * 32];
    __shared__ alignas(16) unsigned short Bs[2][128 * 32];
    const int t = threadIdx.x;
    const int lane = t & 63, wv = t >> 6;
    const int ln = lane & 15, quad = lane >> 4;
    const int wm = wv >> 1, wn = wv & 1;
    const int bm = blockIdx.y * 128, bn = blockIdx.x * 128;

    floatx4 acc[4][4] = {};

    const int srow = t >> 2;
    const int sc = (t & 3) ^ (srow & 3);          // global chunk fetched into slot t&3
    const unsigned short* ga0 = A + (size_t)(bm + srow) * K + sc * 8;
    const unsigned short* ga1 = ga0 + (size_t)64 * K;
    const unsigned short* gb0 = Bt + (size_t)(bn + srow) * K + sc * 8;
    const unsigned short* gb1 = gb0 + (size_t)64 * K;

    gll16(ga0, &As[0][wv * 512]);
    gll16(ga1, &As[0][2048 + wv * 512]);
    gll16(gb0, &Bs[0][wv * 512]);
    gll16(gb1, &Bs[0][2048 + wv * 512]);

    const int sw = ln & 3;                        // read-side swizzle key
    int cur = 0;
    for (int k0 = 0; k0 < K; k0 += 32, cur ^= 1) {
        __syncthreads();
        const int nk = k0 + 32;
        if (nk < K) {
            gll16(ga0 + nk, &As[cur ^ 1][wv * 512]);
            gll16(ga1 + nk, &As[cur ^ 1][2048 + wv * 512]);
            gll16(gb0 + nk, &Bs[cur ^ 1][wv * 512]);
            gll16(gb1 + nk, &Bs[cur ^ 1][2048 + wv * 512]);
        }
        shortx8 af[4], bfr[4];
#pragma unroll
        for (int i = 0; i < 4; ++i)
            af[i] = *(const shortx8*)(&As[cur][(wm * 64 + i * 16 + ln) * 32 + ((quad ^ sw) * 8)]);
#pragma unroll
        for (int j = 0; j < 4; ++j)
            bfr[j] = *(const shortx8*)(&Bs[cur][(wn * 64 + j * 16 + ln) * 32 + ((quad ^ sw) * 8)]);
#pragma unroll
        for (int i = 0; i < 4; ++i)
#pragma unroll
            for (int j = 0; j < 4; ++j)
                acc[i][j] = __builtin_amdgcn_mfma_f32_16x16x32_bf16(af[i], bfr[j], acc[i][j], 0, 0, 0);
    }

#pragma unroll
    for (int i = 0; i < 4; ++i)
#pragma unroll
        for (int j = 0; j < 4; ++j)
#pragma unroll
            for (int r = 0; r < 4; ++r) {
                int row = bm + wm * 64 + i * 16 + quad * 4 + r;
                int col = bn + wn * 64 + j * 16 + ln;
                C[(size_t)row * N + col] = f2bf(acc[i][j][r]);
            }
}

// ---------- GEMM 128x64 tiles (output proj), dbuf + swizzle ----------
__global__ __launch_bounds__(256) void k_gemm_n64(const unsigned short* __restrict__ A,
                                                  const unsigned short* __restrict__ Bt,
                                                  float* __restrict__ C,
                                                  int N, int K) {
    __shared__ alignas(16) unsigned short As[2][128 * 32];
    __shared__ alignas(16) unsigned short Bs[2][64 * 32];
    const int t = threadIdx.x;
    const int lane = t & 63, wv = t >> 6;
    const int ln = lane & 15, quad = lane >> 4;
    const int bm = blockIdx.y * 128, bn = blockIdx.x * 64;

    floatx4 acc[2][4] = {};

    const int srow = t >> 2;
    const int sc = (t & 3) ^ (srow & 3);
    const unsigned short* ga0 = A + (size_t)(bm + srow) * K + sc * 8;
    const unsigned short* ga1 = ga0 + (size_t)64 * K;
    const unsigned short* gb0 = Bt + (size_t)(bn + srow) * K + sc * 8;

    gll16(ga0, &As[0][wv * 512]);
    gll16(ga1, &As[0][2048 + wv * 512]);
    gll16(gb0, &Bs[0][wv * 512]);

    const int sw = ln & 3;
    int cur = 0;
    for (int k0 = 0; k0 < K; k0 += 32, cur ^= 1) {
        __syncthreads();
        const int nk = k0 + 32;
        if (nk < K) {
            gll16(ga0 + nk, &As[cur ^ 1][wv * 512]);
            gll16(ga1 + nk, &As[cur ^ 1][2048 + wv * 512]);
            gll16(gb0 + nk, &Bs[cur ^ 1][wv * 512]);
        }
        shortx8 af[2], bfr[4];
#pragma unroll
        for (int i = 0; i < 2; ++i)
            af[i] = *(const shortx8*)(&As[cur][(wv * 32 + i * 16 + ln) * 32 + ((quad ^ sw) * 8)]);
#pragma unroll
        for (int j = 0; j < 4; ++j)
            bfr[j] = *(const shortx8*)(&Bs[cur][(j * 16 + ln) * 32 + ((quad ^ sw) * 8)]);
#pragma unroll
        for (int i = 0; i < 2; ++i)
#pragma unroll
            for (int j = 0; j < 4; ++j)
                acc[i][j] = __builtin_amdgcn_mfma_f32_16x16x32_bf16(af[i], bfr[j], acc[i][j], 0, 0, 0);
    }

#pragma unroll
    for (int i = 0; i < 2; ++i)
#pragma unroll
        for (int j = 0; j < 4; ++j)
#pragma unroll
            for (int r = 0; r < 4; ++r) {
                int row = bm + wv * 32 + i * 16 + quad * 4 + r;
                int col = bn + j * 16 + ln;
                C[(size_t)row * N + col] = acc[i][j][r];
            }
}

// ---------- fused causal attention + Hadamard ----------
// S^T orientation, 64-row Q tile (grid 32x32 = 1024 blocks, 4/CU).
// K and KR tiles async-staged to LDS via gll16, double-buffered (prefetch kt+1
// during compute of kt). XOR-swizzled 16B chunks (gll16 forbids padding):
// LDS[row][c'] holds global chunk c'^(row&7); reads use (cm^(ln&7)) -> 2-way banks.
// P stays in registers: S^T C-layout (keys quad*4+r) == 16x16x16 B-layout.
__global__ __launch_bounds__(256, 4) void k_attn(const unsigned short* __restrict__ qcat,
                                                 const unsigned short* __restrict__ krT,
                                                 unsigned short* __restrict__ ar) {
    __shared__ alignas(16) unsigned short Kl[2][64 * 64];  // [m][d] swizzled
    __shared__ alignas(16) unsigned short Rl[2][64 * 64];  // [d][m] swizzled

    const int t = threadIdx.x;
    const int lane = t & 63, w = t >> 6;
    const int ln = lane & 15, quad = lane >> 4;
    const int bh = blockIdx.y;
    const int b = bh >> 4, h = bh & 15;
    const int qx = blockIdx.x;
    const int qt = (qx & 1) ? 31 - (qx >> 1) : (qx >> 1);  // pairwise load balance
    const int l0 = qt * 64;
    const size_t baserow = (size_t)b * 2048;

    // Q B-frags (loop-invariant): col q = ln, k(d) = quad*8+i (+32)
    const int qrow = l0 + w * 16 + ln;
    const unsigned short* qp = qcat + (baserow + qrow) * 4096 + h * 64 + quad * 8;
    const shortx8 aq0 = *(const shortx8*)(qp);
    const shortx8 aq1 = *(const shortx8*)(qp + 32);

    floatx4 acc_o[4] = {};   // [jd]; lane: col q=ln, rows d = jd*16+quad*4+r
    float lsum = 0.f;

    // staging: thread t -> LDS slot row=t>>3 (+32), chunk slot t&7; fetches global
    // chunk (t&7)^(row&7). 2 gll16 per tile (rows 0-31, 32-63), 16B/lane.
    const int srow = t >> 3;
    const int sc = (t & 7) ^ (srow & 7);
    const unsigned short* gK = qcat + (baserow + srow) * 4096 + 1024 + h * 64 + sc * 8;
    const unsigned short* gR = krT + ((size_t)bh * 64 + srow) * 2048 + sc * 8;

    auto stage = [&](int kt, int buf) {
        gll16(gK + (size_t)(kt * 64) * 4096,      &Kl[buf][w * 512]);
        gll16(gK + (size_t)(kt * 64 + 32) * 4096, &Kl[buf][2048 + w * 512]);
        gll16(gR + kt * 64,                       &Rl[buf][w * 512]);
        gll16(gR + (size_t)32 * 2048 + kt * 64,   &Rl[buf][2048 + w * 512]);
    };

    stage(0, 0);
    const int swz = ln & 7;   // read-side swizzle key (row&7 == ln&7 for 16-strided rows)
    int cur = 0;
    for (int kt = 0; kt <= qt; ++kt, cur ^= 1) {
        __syncthreads();                 // drains DMA; prev iter's LDS reads done
        if (kt < qt) stage(kt + 1, cur ^ 1);
        const unsigned short* Kc = Kl[cur];
        const unsigned short* Rc = Rl[cur];
        const bool diag = (kt == qt);

        // S^T = K·Q^T; exp2; pack P into registers
        shortx4 pk[4];
#pragma unroll
        for (int jk = 0; jk < 4; ++jk) {
            const int kr0 = (jk * 16 + ln) * 64;
            shortx8 kf0 = *(const shortx8*)(Kc + kr0 + ((quad ^ swz) * 8));
            shortx8 kf1 = *(const shortx8*)(Kc + kr0 + (((4 + quad) ^ swz) * 8));
            floatx4 z = {0.f, 0.f, 0.f, 0.f};
            z = __builtin_amdgcn_mfma_f32_16x16x32_bf16(kf0, aq0, z, 0, 0, 0);
            z = __builtin_amdgcn_mfma_f32_16x16x32_bf16(kf1, aq1, z, 0, 0, 0);
            const int keyb = kt * 64 + jk * 16 + quad * 4;   // global key (+r)
#pragma unroll
            for (int r = 0; r < 4; ++r) {
                float e = exp2fast(z[r]);
                e = (diag && (keyb + r > qrow)) ? 0.f : e;   // causal: key > q
                lsum += e;
                pk[jk][r] = (short)f2bf(e);
            }
        }

        // PV: O^T += KR^T · P^T  (A from LDS, B=pk in regs)
#pragma unroll
        for (int jk = 0; jk < 4; ++jk) {
            const int cm = jk * 2 + (quad >> 1);
#pragma unroll
            for (int jd = 0; jd < 4; ++jd) {
                shortx4 krf = *(const shortx4*)(Rc + (jd * 16 + ln) * 64 +
                                                ((cm ^ swz) * 8) + (quad & 1) * 4);
                acc_o[jd] = mfma16(krf, pk[jk], acc_o[jd]);
            }
        }
    }

    // epilogue: reduce lsum over quads, /sum, Hadamard qr, packed b64 stores
    float s = lsum;
    s += __shfl_xor(s, 16);
    s += __shfl_xor(s, 32);
    const float inv = 1.0f / s;
    const unsigned short* qr = qcat + (baserow + qrow) * 4096 + 2048 + h * 64;
    unsigned short* arow = ar + (baserow + qrow) * 1024 + h * 64;
#pragma unroll
    for (int jd = 0; jd < 4; ++jd) {
        const int d0 = jd * 16 + quad * 4;
        shortx4 qv = *(const shortx4*)(qr + d0);
        shortx4 o;
#pragma unroll
        for (int r = 0; r < 4; ++r)
            o[r] = (short)f2bf(acc_o[jd][r] * inv * bf2f((unsigned short)qv[r]));
        *(shortx4*)(arow + d0) = o;
    }
}

extern "C" void kernel_launch(void* const* d_in, const int* in_sizes, int n_in,
                              void* d_out, int out_size, void* d_ws, size_t ws_size,
                              hipStream_t stream) {
    const float* x   = (const float*)d_in[0];
    const float* wq  = (const float*)d_in[1];
    const float* wk  = (const float*)d_in[2];
    const float* wqr = (const float*)d_in[3];
    const float* wkr = (const float*)d_in[4];
    const float* wo  = (const float*)d_in[5];
    float* out = (float*)d_out;

    unsigned short* xb    = (unsigned short*)d_ws;
    unsigned short* wcatT = xb + (size_t)4096 * 1024;
    unsigned short* qcat  = wcatT + (size_t)4096 * 1024;
    unsigned short* wotT  = qcat + (size_t)4096 * 4096;
    unsigned short* krT   = wcatT;   // wcatT dead after proj GEMM
    unsigned short* arb   = xb;      // xb dead after proj GEMM

    k_cvt_x<<<4096, 256, 0, stream>>>(x, xb);
    k_cvt_w5<<<dim3(16, 16, 5), 256, 0, stream>>>(wq, wk, wqr, wkr, wo, wcatT, wotT);
    k_gemm_bt<<<dim3(32, 32), 256, 0, stream>>>(xb, wcatT, qcat, 4096, 1024);
    k_trans<<<dim3(32, 32), 256, 0, stream>>>(qcat, krT);
    k_attn<<<dim3(32, 32), 256, 0, stream>>>(qcat, krT, arb);
    k_gemm_n64<<<dim3(16, 32), 256, 0, stream>>>(arb, wotT, out, 1024, 1024);
}

// Round 7
// 215.692 us; speedup vs baseline: 1.5742x; 1.0008x over previous
//
#include <hip/hip_runtime.h>
#include <stdint.h>

// B=2, L=2048, DM=1024, H=16, D=64
// ws layout (50 MB):
//   xb    bf16[4096][1024]  x converted            (reused as arb after proj GEMM)
//   wcatT bf16[4096][1024]  [wq*0.125*log2e|wk|wqr|wkr]^T (reused as krT)
//   qcat  bf16[4096][4096]  q|k|qr|kr col blocks
//   wotT  bf16[1024][1024]  wo^T
// krT layout: [b*16+h][64 d][2048 l]

typedef __attribute__((ext_vector_type(4))) float floatx4;
typedef __attribute__((ext_vector_type(8))) short shortx8;
typedef __attribute__((ext_vector_type(4))) short shortx4;

__device__ __forceinline__ unsigned short f2bf(float f) {
    unsigned u = __float_as_uint(f);
    u += 0x7fffu + ((u >> 16) & 1u);   // RNE
    return (unsigned short)(u >> 16);
}
__device__ __forceinline__ float bf2f(unsigned short s) {
    return __uint_as_float(((unsigned)s) << 16);
}
__device__ __forceinline__ float exp2fast(float x) {
#if __has_builtin(__builtin_amdgcn_exp2f)
    return __builtin_amdgcn_exp2f(x);
#else
    return __expf(x * 0.69314718056f);
#endif
}
// pack hi16(e0),hi16(e1) -> one dword via v_perm (bf16 truncation, 1 VALU op)
__device__ __forceinline__ unsigned pkbf(float e0, float e1) {
    return __builtin_amdgcn_perm(__float_as_uint(e1), __float_as_uint(e0), 0x07060302u);
}
// PV MFMA: D += A(4 bf16, k=quad*4+i) * B(4 bf16, k=quad*4+i)
__device__ __forceinline__ floatx4 mfma16(shortx4 a, shortx4 b, floatx4 c) {
#if __has_builtin(__builtin_amdgcn_mfma_f32_16x16x16bf16_1k)
    return __builtin_amdgcn_mfma_f32_16x16x16bf16_1k(a, b, c, 0, 0, 0);
#else
    shortx8 a8 = {a[0], a[1], a[2], a[3], 0, 0, 0, 0};
    shortx8 b8 = {b[0], b[1], b[2], b[3], 0, 0, 0, 0};
    return __builtin_amdgcn_mfma_f32_16x16x32_bf16(a8, b8, c, 0, 0, 0);
#endif
}
// async global->LDS, 16B/lane; lds dest = wave-uniform base + lane*16
__device__ __forceinline__ void gll16(const void* g, void* l) {
    __builtin_amdgcn_global_load_lds(
        (const __attribute__((address_space(1))) unsigned int*)g,
        (__attribute__((address_space(3))) unsigned int*)l, 16, 0, 0);
}

// ---------- x -> bf16 (coalesced) ----------
__global__ void k_cvt_x(const float* __restrict__ x, unsigned short* __restrict__ xb) {
    int i = (blockIdx.x * 256 + threadIdx.x) * 4;
    float4 v = *(const float4*)(x + i);
    ushort4 o;
    o.x = f2bf(v.x); o.y = f2bf(v.y); o.z = f2bf(v.z); o.w = f2bf(v.w);
    *(ushort4*)(xb + i) = o;
}

// ---------- all 5 weights: fp32 [k][n] -> bf16 [n][k], LDS-tiled; z selects W ----------
__global__ __launch_bounds__(256) void k_cvt_w5(const float* __restrict__ wq,
                                                const float* __restrict__ wk,
                                                const float* __restrict__ wqr,
                                                const float* __restrict__ wkr,
                                                const float* __restrict__ wo,
                                                unsigned short* __restrict__ wcatT,
                                                unsigned short* __restrict__ wotT) {
    __shared__ unsigned short Tl[64 * 65];
    const int t = threadIdx.x;
    const int kt = blockIdx.x * 64, nt = blockIdx.y * 64;
    const int z = blockIdx.z;
    const float* W = (z == 0) ? wq : (z == 1) ? wk : (z == 2) ? wqr : (z == 3) ? wkr : wo;
    unsigned short* outT = (z < 4) ? (wcatT + (size_t)z * 1024 * 1024) : wotT;
    // fold SDPA scale AND log2(e) into wq: scores in log2 domain, p = 2^z
    const float scale = (z == 0) ? 0.18033688f : 1.0f;   // 0.125 * 1.44269504
    {
        const int kl = t >> 3, nc = (t & 7) * 8;
        const float* src = W + (size_t)(kt + kl) * 1024 + nt + nc;
        float a[8], b[8];
        *(float4*)(a)     = *(const float4*)(src);
        *(float4*)(a + 4) = *(const float4*)(src + 4);
        *(float4*)(b)     = *(const float4*)(src + 32 * 1024);
        *(float4*)(b + 4) = *(const float4*)(src + 32 * 1024 + 4);
#pragma unroll
        for (int i = 0; i < 8; ++i) {
            Tl[kl * 65 + nc + i]        = f2bf(a[i] * scale);
            Tl[(kl + 32) * 65 + nc + i] = f2bf(b[i] * scale);
        }
    }
    __syncthreads();
    {
        const int n = t >> 2, kc = (t & 3) * 16;
        shortx8 o0, o1;
#pragma unroll
        for (int i = 0; i < 8; ++i) {
            o0[i] = (short)Tl[(kc + i) * 65 + n];
            o1[i] = (short)Tl[(kc + 8 + i) * 65 + n];
        }
        unsigned short* dst = outT + (size_t)(nt + n) * 1024 + kt + kc;
        *(shortx8*)(dst)     = o0;
        *(shortx8*)(dst + 8) = o1;
    }
}

// ---------- KR (qcat cols 3072..4095, [l][h*64+d]) -> krT [bh][d][l] ----------
__global__ __launch_bounds__(256) void k_trans(const unsigned short* __restrict__ qcat,
                                               unsigned short* __restrict__ krT) {
    __shared__ unsigned short Tl[64 * 65];
    const int t = threadIdx.x;
    const int mt = blockIdx.x * 64;
    const int bh = blockIdx.y;
    const int b = bh >> 4, h = bh & 15;
    {
        const int ml = t >> 3, dc = (t & 7) * 8;
        const unsigned short* src =
            qcat + ((size_t)b * 2048 + mt + ml) * 4096 + 3072 + h * 64 + dc;
        shortx8 v0 = *(const shortx8*)(src);
        shortx8 v1 = *(const shortx8*)(src + (size_t)32 * 4096);
#pragma unroll
        for (int i = 0; i < 8; ++i) {
            Tl[ml * 65 + dc + i]        = (unsigned short)v0[i];
            Tl[(ml + 32) * 65 + dc + i] = (unsigned short)v1[i];
        }
    }
    __syncthreads();
    {
        const int d = t >> 2, mc = (t & 3) * 16;
        shortx8 o0, o1;
#pragma unroll
        for (int i = 0; i < 8; ++i) {
            o0[i] = (short)Tl[(mc + i) * 65 + d];
            o1[i] = (short)Tl[(mc + 8 + i) * 65 + d];
        }
        unsigned short* dst = krT + ((size_t)bh * 64 + d) * 2048 + mt + mc;
        *(shortx8*)(dst)     = o0;
        *(shortx8*)(dst + 8) = o1;
    }
}

// ---------- GEMM 128x128x(BK=32), dbuf gll16, bijective XOR swizzle ----------
// Row stride = 32 shorts (16 dwords) -> bank group = 4*(ln&1) + slot.
// slot = chunk ^ ((row>>1)&3) makes every aligned 8-lane phase a permutation
// of all 8 bank groups (conflict-free), unlike the old (row&3) key (2-way pairs).
__global__ __launch_bounds__(256) void k_gemm_bt(const unsigned short* __restrict__ A,
                                                 const unsigned short* __restrict__ Bt,
                                                 unsigned short* __restrict__ C,
                                                 int N, int K) {
    __shared__ alignas(16) unsigned short As[2][128 * 32];
    __shared__ alignas(16) unsigned short Bs[2][128 * 32];
    const int t = threadIdx.x;
    const int lane = t & 63, wv = t >> 6;
    const int ln = lane & 15, quad = lane >> 4;
    const int wm = wv >> 1, wn = wv & 1;
    const int bm = blockIdx.y * 128, bn = blockIdx.x * 128;

    floatx4 acc[4][4] = {};

    const int srow = t >> 2;
    const int sc = (t & 3) ^ ((srow >> 1) & 3);   // global chunk fetched into slot t&3
    const unsigned short* ga0 = A + (size_t)(bm + srow) * K + sc * 8;
    const unsigned short* ga1 = ga0 + (size_t)64 * K;
    const unsigned short* gb0 = Bt + (size_t)(bn + srow) * K + sc * 8;
    const unsigned short* gb1 = gb0 + (size_t)64 * K;

    gll16(ga0, &As[0][wv * 512]);
    gll16(ga1, &As[0][2048 + wv * 512]);
    gll16(gb0, &Bs[0][wv * 512]);
    gll16(gb1, &Bs[0][2048 + wv * 512]);

    const int sw = (ln >> 1) & 3;                 // read-side swizzle key
    int cur = 0;
    for (int k0 = 0; k0 < K; k0 += 32, cur ^= 1) {
        __syncthreads();
        const int nk = k0 + 32;
        if (nk < K) {
            gll16(ga0 + nk, &As[cur ^ 1][wv * 512]);
            gll16(ga1 + nk, &As[cur ^ 1][2048 + wv * 512]);
            gll16(gb0 + nk, &Bs[cur ^ 1][wv * 512]);
            gll16(gb1 + nk, &Bs[cur ^ 1][2048 + wv * 512]);
        }
        shortx8 af[4], bfr[4];
#pragma unroll
        for (int i = 0; i < 4; ++i)
            af[i] = *(const shortx8*)(&As[cur][(wm * 64 + i * 16 + ln) * 32 + ((quad ^ sw) * 8)]);
#pragma unroll
        for (int j = 0; j < 4; ++j)
            bfr[j] = *(const shortx8*)(&Bs[cur][(wn * 64 + j * 16 + ln) * 32 + ((quad ^ sw) * 8)]);
#pragma unroll
        for (int i = 0; i < 4; ++i)
#pragma unroll
            for (int j = 0; j < 4; ++j)
                acc[i][j] = __builtin_amdgcn_mfma_f32_16x16x32_bf16(af[i], bfr[j], acc[i][j], 0, 0, 0);
    }

#pragma unroll
    for (int i = 0; i < 4; ++i)
#pragma unroll
        for (int j = 0; j < 4; ++j)
#pragma unroll
            for (int r = 0; r < 4; ++r) {
                int row = bm + wm * 64 + i * 16 + quad * 4 + r;
                int col = bn + wn * 64 + j * 16 + ln;
                C[(size_t)row * N + col] = f2bf(acc[i][j][r]);
            }
}

// ---------- GEMM 128x64 tiles (output proj), dbuf + bijective swizzle ----------
__global__ __launch_bounds__(256) void k_gemm_n64(const unsigned short* __restrict__ A,
                                                  const unsigned short* __restrict__ Bt,
                                                  float* __restrict__ C,
                                                  int N, int K) {
    __shared__ alignas(16) unsigned short As[2][128 * 32];
    __shared__ alignas(16) unsigned short Bs[2][64 * 32];
    const int t = threadIdx.x;
    const int lane = t & 63, wv = t >> 6;
    const int ln = lane & 15, quad = lane >> 4;
    const int bm = blockIdx.y * 128, bn = blockIdx.x * 64;

    floatx4 acc[2][4] = {};

    const int srow = t >> 2;
    const int sc = (t & 3) ^ ((srow >> 1) & 3);
    const unsigned short* ga0 = A + (size_t)(bm + srow) * K + sc * 8;
    const unsigned short* ga1 = ga0 + (size_t)64 * K;
    const unsigned short* gb0 = Bt + (size_t)(bn + srow) * K + sc * 8;

    gll16(ga0, &As[0][wv * 512]);
    gll16(ga1, &As[0][2048 + wv * 512]);
    gll16(gb0, &Bs[0][wv * 512]);

    const int sw = (ln >> 1) & 3;
    int cur = 0;
    for (int k0 = 0; k0 < K; k0 += 32, cur ^= 1) {
        __syncthreads();
        const int nk = k0 + 32;
        if (nk < K) {
            gll16(ga0 + nk, &As[cur ^ 1][wv * 512]);
            gll16(ga1 + nk, &As[cur ^ 1][2048 + wv * 512]);
            gll16(gb0 + nk, &Bs[cur ^ 1][wv * 512]);
        }
        shortx8 af[2], bfr[4];
#pragma unroll
        for (int i = 0; i < 2; ++i)
            af[i] = *(const shortx8*)(&As[cur][(wv * 32 + i * 16 + ln) * 32 + ((quad ^ sw) * 8)]);
#pragma unroll
        for (int j = 0; j < 4; ++j)
            bfr[j] = *(const shortx8*)(&Bs[cur][(j * 16 + ln) * 32 + ((quad ^ sw) * 8)]);
#pragma unroll
        for (int i = 0; i < 2; ++i)
#pragma unroll
            for (int j = 0; j < 4; ++j)
                acc[i][j] = __builtin_amdgcn_mfma_f32_16x16x32_bf16(af[i], bfr[j], acc[i][j], 0, 0, 0);
    }

#pragma unroll
    for (int i = 0; i < 2; ++i)
#pragma unroll
        for (int j = 0; j < 4; ++j)
#pragma unroll
            for (int r = 0; r < 4; ++r) {
                int row = bm + wv * 32 + i * 16 + quad * 4 + r;
                int col = bn + j * 16 + ln;
                C[(size_t)row * N + col] = acc[i][j][r];
            }
}

// ---------- fused causal attention + Hadamard ----------
// S^T orientation, 64-row Q tile (grid 32x32 = 1024 blocks, 4/CU).
// K/KR async-staged via gll16, double-buffered. XOR-swizzled 16B chunks:
// row stride 64 shorts == 0 mod 32 dwords -> slot IS the bank group, and
// slot = chunk^(ln&7) is already a per-phase permutation (conflict-free).
// P stays in registers (truncation-packed via v_perm): S^T C-layout keys
// (quad*4+r) == 16x16x16 B-layout k.
__global__ __launch_bounds__(256, 4) void k_attn(const unsigned short* __restrict__ qcat,
                                                 const unsigned short* __restrict__ krT,
                                                 unsigned short* __restrict__ ar) {
    __shared__ alignas(16) unsigned short Kl[2][64 * 64];  // [m][d] swizzled
    __shared__ alignas(16) unsigned short Rl[2][64 * 64];  // [d][m] swizzled

    const int t = threadIdx.x;
    const int lane = t & 63, w = t >> 6;
    const int ln = lane & 15, quad = lane >> 4;
    const int bh = blockIdx.y;
    const int b = bh >> 4, h = bh & 15;
    const int qx = blockIdx.x;
    const int qt = (qx & 1) ? 31 - (qx >> 1) : (qx >> 1);  // pairwise load balance
    const int l0 = qt * 64;
    const size_t baserow = (size_t)b * 2048;

    // Q B-frags (loop-invariant): col q = ln, k(d) = quad*8+i (+32)
    const int qrow = l0 + w * 16 + ln;
    const unsigned short* qp = qcat + (baserow + qrow) * 4096 + h * 64 + quad * 8;
    const shortx8 aq0 = *(const shortx8*)(qp);
    const shortx8 aq1 = *(const shortx8*)(qp + 32);

    floatx4 acc_o[4] = {};   // [jd]; lane: col q=ln, rows d = jd*16+quad*4+r
    float lsum = 0.f;

    const int srow = t >> 3;
    const int sc = (t & 7) ^ (srow & 7);
    const unsigned short* gK = qcat + (baserow + srow) * 4096 + 1024 + h * 64 + sc * 8;
    const unsigned short* gR = krT + ((size_t)bh * 64 + srow) * 2048 + sc * 8;

    auto stage = [&](int kt, int buf) {
        gll16(gK + (size_t)(kt * 64) * 4096,      &Kl[buf][w * 512]);
        gll16(gK + (size_t)(kt * 64 + 32) * 4096, &Kl[buf][2048 + w * 512]);
        gll16(gR + kt * 64,                       &Rl[buf][w * 512]);
        gll16(gR + (size_t)32 * 2048 + kt * 64,   &Rl[buf][2048 + w * 512]);
    };

    stage(0, 0);
    const int swz = ln & 7;   // read-side swizzle key
    int cur = 0;
    for (int kt = 0; kt <= qt; ++kt, cur ^= 1) {
        __syncthreads();                 // drains DMA; prev iter's LDS reads done
        if (kt < qt) stage(kt + 1, cur ^ 1);
        const unsigned short* Kc = Kl[cur];
        const unsigned short* Rc = Rl[cur];
        const bool diag = (kt == qt);

        // S^T = K·Q^T; exp2; truncation-pack P into registers (1 v_perm / pair)
        shortx4 pk[4];
#pragma unroll
        for (int jk = 0; jk < 4; ++jk) {
            const int kr0 = (jk * 16 + ln) * 64;
            shortx8 kf0 = *(const shortx8*)(Kc + kr0 + ((quad ^ swz) * 8));
            shortx8 kf1 = *(const shortx8*)(Kc + kr0 + (((4 + quad) ^ swz) * 8));
            floatx4 z = {0.f, 0.f, 0.f, 0.f};
            z = __builtin_amdgcn_mfma_f32_16x16x32_bf16(kf0, aq0, z, 0, 0, 0);
            z = __builtin_amdgcn_mfma_f32_16x16x32_bf16(kf1, aq1, z, 0, 0, 0);
            float e0 = exp2fast(z[0]);
            float e1 = exp2fast(z[1]);
            float e2 = exp2fast(z[2]);
            float e3 = exp2fast(z[3]);
            if (diag) {
                const int keyb = kt * 64 + jk * 16 + quad * 4;   // global key (+r)
                e0 = (keyb + 0 > qrow) ? 0.f : e0;
                e1 = (keyb + 1 > qrow) ? 0.f : e1;
                e2 = (keyb + 2 > qrow) ? 0.f : e2;
                e3 = (keyb + 3 > qrow) ? 0.f : e3;
            }
            lsum += (e0 + e1) + (e2 + e3);
            struct U2 { unsigned a, b; } u{pkbf(e0, e1), pkbf(e2, e3)};
            pk[jk] = __builtin_bit_cast(shortx4, u);
        }

        // PV: O^T += KR^T · P^T  (A from LDS, B=pk in regs)
#pragma unroll
        for (int jk = 0; jk < 4; ++jk) {
            const int cm = jk * 2 + (quad >> 1);
#pragma unroll
            for (int jd = 0; jd < 4; ++jd) {
                shortx4 krf = *(const shortx4*)(Rc + (jd * 16 + ln) * 64 +
                                                ((cm ^ swz) * 8) + (quad & 1) * 4);
                acc_o[jd] = mfma16(krf, pk[jk], acc_o[jd]);
            }
        }
    }

    // epilogue: reduce lsum over quads, /sum, Hadamard qr, packed b64 stores
    float s = lsum;
    s += __shfl_xor(s, 16);
    s += __shfl_xor(s, 32);
    const float inv = 1.0f / s;
    const unsigned short* qr = qcat + (baserow + qrow) * 4096 + 2048 + h * 64;
    unsigned short* arow = ar + (baserow + qrow) * 1024 + h * 64;
#pragma unroll
    for (int jd = 0; jd < 4; ++jd) {
        const int d0 = jd * 16 + quad * 4;
        shortx4 qv = *(const shortx4*)(qr + d0);
        shortx4 o;
#pragma unroll
        for (int r = 0; r < 4; ++r)
            o[r] = (short)f2bf(acc_o[jd][r] * inv * bf2f((unsigned short)qv[r]));
        *(shortx4*)(arow + d0) = o;
    }
}

extern "C" void kernel_launch(void* const* d_in, const int* in_sizes, int n_in,
                              void* d_out, int out_size, void* d_ws, size_t ws_size,
                              hipStream_t stream) {
    const float* x   = (const float*)d_in[0];
    const float* wq  = (const float*)d_in[1];
    const float* wk  = (const float*)d_in[2];
    const float* wqr = (const float*)d_in[3];
    const float* wkr = (const float*)d_in[4];
    const float* wo  = (const float*)d_in[5];
    float* out = (float*)d_out;

    unsigned short* xb    = (unsigned short*)d_ws;
    unsigned short* wcatT = xb + (size_t)4096 * 1024;
    unsigned short* qcat  = wcatT + (size_t)4096 * 1024;
    unsigned short* wotT  = qcat + (size_t)4096 * 4096;
    unsigned short* krT   = wcatT;   // wcatT dead after proj GEMM
    unsigned short* arb   = xb;      // xb dead after proj GEMM

    k_cvt_x<<<4096, 256, 0, stream>>>(x, xb);
    k_cvt_w5<<<dim3(16, 16, 5), 256, 0, stream>>>(wq, wk, wqr, wkr, wo, wcatT, wotT);
    k_gemm_bt<<<dim3(32, 32), 256, 0, stream>>>(xb, wcatT, qcat, 4096, 1024);
    k_trans<<<dim3(32, 32), 256, 0, stream>>>(qcat, krT);
    k_attn<<<dim3(32, 32), 256, 0, stream>>>(qcat, krT, arb);
    k_gemm_n64<<<dim3(16, 32), 256, 0, stream>>>(arb, wotT, out, 1024, 1024);
}

// Round 8
// 201.733 us; speedup vs baseline: 1.6831x; 1.0692x over previous
//
#include <hip/hip_runtime.h>
#include <stdint.h>

// B=2, L=2048, DM=1024, H=16, D=64
// ws layout (50 MB):
//   xb    bf16[4096][1024]  x converted            (reused as arb after proj GEMM)
//   wcatT bf16[4096][1024]  [wq*0.125*log2e|wk|wqr|wkr]^T (reused as krT)
//   qcat  bf16[4096][4096]  q|k|qr|kr col blocks
//   wotT  bf16[1024][1024]  wo^T
// krT layout: [b*16+h][64 d][2048 l]

typedef __attribute__((ext_vector_type(4))) float floatx4;
typedef __attribute__((ext_vector_type(8))) short shortx8;
typedef __attribute__((ext_vector_type(4))) short shortx4;

__device__ __forceinline__ unsigned short f2bf(float f) {
    unsigned u = __float_as_uint(f);
    u += 0x7fffu + ((u >> 16) & 1u);   // RNE
    return (unsigned short)(u >> 16);
}
__device__ __forceinline__ float bf2f(unsigned short s) {
    return __uint_as_float(((unsigned)s) << 16);
}
__device__ __forceinline__ float exp2fast(float x) {
#if __has_builtin(__builtin_amdgcn_exp2f)
    return __builtin_amdgcn_exp2f(x);
#else
    return __expf(x * 0.69314718056f);
#endif
}
// pack hi16(e0),hi16(e1) -> one dword via v_perm (bf16 truncation, 1 VALU op)
__device__ __forceinline__ unsigned pkbf(float e0, float e1) {
    return __builtin_amdgcn_perm(__float_as_uint(e1), __float_as_uint(e0), 0x07060302u);
}
// PV MFMA: D += A(4 bf16, k=quad*4+i) * B(4 bf16, k=quad*4+i)
__device__ __forceinline__ floatx4 mfma16(shortx4 a, shortx4 b, floatx4 c) {
#if __has_builtin(__builtin_amdgcn_mfma_f32_16x16x16bf16_1k)
    return __builtin_amdgcn_mfma_f32_16x16x16bf16_1k(a, b, c, 0, 0, 0);
#else
    shortx8 a8 = {a[0], a[1], a[2], a[3], 0, 0, 0, 0};
    shortx8 b8 = {b[0], b[1], b[2], b[3], 0, 0, 0, 0};
    return __builtin_amdgcn_mfma_f32_16x16x32_bf16(a8, b8, c, 0, 0, 0);
#endif
}
// async global->LDS, 16B/lane; lds dest = wave-uniform base + lane*16
__device__ __forceinline__ void gll16(const void* g, void* l) {
    __builtin_amdgcn_global_load_lds(
        (const __attribute__((address_space(1))) unsigned int*)g,
        (__attribute__((address_space(3))) unsigned int*)l, 16, 0, 0);
}

// ---------- x -> bf16 (coalesced) ----------
__global__ void k_cvt_x(const float* __restrict__ x, unsigned short* __restrict__ xb) {
    int i = (blockIdx.x * 256 + threadIdx.x) * 4;
    float4 v = *(const float4*)(x + i);
    ushort4 o;
    o.x = f2bf(v.x); o.y = f2bf(v.y); o.z = f2bf(v.z); o.w = f2bf(v.w);
    *(ushort4*)(xb + i) = o;
}

// ---------- all 5 weights: fp32 [k][n] -> bf16 [n][k], LDS-tiled; z selects W ----------
__global__ __launch_bounds__(256) void k_cvt_w5(const float* __restrict__ wq,
                                                const float* __restrict__ wk,
                                                const float* __restrict__ wqr,
                                                const float* __restrict__ wkr,
                                                const float* __restrict__ wo,
                                                unsigned short* __restrict__ wcatT,
                                                unsigned short* __restrict__ wotT) {
    __shared__ unsigned short Tl[64 * 65];
    const int t = threadIdx.x;
    const int kt = blockIdx.x * 64, nt = blockIdx.y * 64;
    const int z = blockIdx.z;
    const float* W = (z == 0) ? wq : (z == 1) ? wk : (z == 2) ? wqr : (z == 3) ? wkr : wo;
    unsigned short* outT = (z < 4) ? (wcatT + (size_t)z * 1024 * 1024) : wotT;
    // fold SDPA scale AND log2(e) into wq: scores in log2 domain, p = 2^z
    const float scale = (z == 0) ? 0.18033688f : 1.0f;   // 0.125 * 1.44269504
    {
        const int kl = t >> 3, nc = (t & 7) * 8;
        const float* src = W + (size_t)(kt + kl) * 1024 + nt + nc;
        float a[8], b[8];
        *(float4*)(a)     = *(const float4*)(src);
        *(float4*)(a + 4) = *(const float4*)(src + 4);
        *(float4*)(b)     = *(const float4*)(src + 32 * 1024);
        *(float4*)(b + 4) = *(const float4*)(src + 32 * 1024 + 4);
#pragma unroll
        for (int i = 0; i < 8; ++i) {
            Tl[kl * 65 + nc + i]        = f2bf(a[i] * scale);
            Tl[(kl + 32) * 65 + nc + i] = f2bf(b[i] * scale);
        }
    }
    __syncthreads();
    {
        const int n = t >> 2, kc = (t & 3) * 16;
        shortx8 o0, o1;
#pragma unroll
        for (int i = 0; i < 8; ++i) {
            o0[i] = (short)Tl[(kc + i) * 65 + n];
            o1[i] = (short)Tl[(kc + 8 + i) * 65 + n];
        }
        unsigned short* dst = outT + (size_t)(nt + n) * 1024 + kt + kc;
        *(shortx8*)(dst)     = o0;
        *(shortx8*)(dst + 8) = o1;
    }
}

// ---------- KR (qcat cols 3072..4095, [l][h*64+d]) -> krT [bh][d][l] ----------
__global__ __launch_bounds__(256) void k_trans(const unsigned short* __restrict__ qcat,
                                               unsigned short* __restrict__ krT) {
    __shared__ unsigned short Tl[64 * 65];
    const int t = threadIdx.x;
    const int mt = blockIdx.x * 64;
    const int bh = blockIdx.y;
    const int b = bh >> 4, h = bh & 15;
    {
        const int ml = t >> 3, dc = (t & 7) * 8;
        const unsigned short* src =
            qcat + ((size_t)b * 2048 + mt + ml) * 4096 + 3072 + h * 64 + dc;
        shortx8 v0 = *(const shortx8*)(src);
        shortx8 v1 = *(const shortx8*)(src + (size_t)32 * 4096);
#pragma unroll
        for (int i = 0; i < 8; ++i) {
            Tl[ml * 65 + dc + i]        = (unsigned short)v0[i];
            Tl[(ml + 32) * 65 + dc + i] = (unsigned short)v1[i];
        }
    }
    __syncthreads();
    {
        const int d = t >> 2, mc = (t & 3) * 16;
        shortx8 o0, o1;
#pragma unroll
        for (int i = 0; i < 8; ++i) {
            o0[i] = (short)Tl[(mc + i) * 65 + d];
            o1[i] = (short)Tl[(mc + 8 + i) * 65 + d];
        }
        unsigned short* dst = krT + ((size_t)bh * 64 + d) * 2048 + mt + mc;
        *(shortx8*)(dst)     = o0;
        *(shortx8*)(dst + 8) = o1;
    }
}

// ---------- GEMM 128x128x(BK=32), dbuf gll16, bijective XOR swizzle ----------
__global__ __launch_bounds__(256) void k_gemm_bt(const unsigned short* __restrict__ A,
                                                 const unsigned short* __restrict__ Bt,
                                                 unsigned short* __restrict__ C,
                                                 int N, int K) {
    __shared__ alignas(16) unsigned short As[2][128 * 32];
    __shared__ alignas(16) unsigned short Bs[2][128 * 32];
    const int t = threadIdx.x;
    const int lane = t & 63, wv = t >> 6;
    const int ln = lane & 15, quad = lane >> 4;
    const int wm = wv >> 1, wn = wv & 1;
    const int bm = blockIdx.y * 128, bn = blockIdx.x * 128;

    floatx4 acc[4][4] = {};

    const int srow = t >> 2;
    const int sc = (t & 3) ^ ((srow >> 1) & 3);   // global chunk fetched into slot t&3
    const unsigned short* ga0 = A + (size_t)(bm + srow) * K + sc * 8;
    const unsigned short* ga1 = ga0 + (size_t)64 * K;
    const unsigned short* gb0 = Bt + (size_t)(bn + srow) * K + sc * 8;
    const unsigned short* gb1 = gb0 + (size_t)64 * K;

    gll16(ga0, &As[0][wv * 512]);
    gll16(ga1, &As[0][2048 + wv * 512]);
    gll16(gb0, &Bs[0][wv * 512]);
    gll16(gb1, &Bs[0][2048 + wv * 512]);

    const int sw = (ln >> 1) & 3;                 // read-side swizzle key
    int cur = 0;
    for (int k0 = 0; k0 < K; k0 += 32, cur ^= 1) {
        __syncthreads();
        const int nk = k0 + 32;
        if (nk < K) {
            gll16(ga0 + nk, &As[cur ^ 1][wv * 512]);
            gll16(ga1 + nk, &As[cur ^ 1][2048 + wv * 512]);
            gll16(gb0 + nk, &Bs[cur ^ 1][wv * 512]);
            gll16(gb1 + nk, &Bs[cur ^ 1][2048 + wv * 512]);
        }
        shortx8 af[4], bfr[4];
#pragma unroll
        for (int i = 0; i < 4; ++i)
            af[i] = *(const shortx8*)(&As[cur][(wm * 64 + i * 16 + ln) * 32 + ((quad ^ sw) * 8)]);
#pragma unroll
        for (int j = 0; j < 4; ++j)
            bfr[j] = *(const shortx8*)(&Bs[cur][(wn * 64 + j * 16 + ln) * 32 + ((quad ^ sw) * 8)]);
#pragma unroll
        for (int i = 0; i < 4; ++i)
#pragma unroll
            for (int j = 0; j < 4; ++j)
                acc[i][j] = __builtin_amdgcn_mfma_f32_16x16x32_bf16(af[i], bfr[j], acc[i][j], 0, 0, 0);
    }

#pragma unroll
    for (int i = 0; i < 4; ++i)
#pragma unroll
        for (int j = 0; j < 4; ++j)
#pragma unroll
            for (int r = 0; r < 4; ++r) {
                int row = bm + wm * 64 + i * 16 + quad * 4 + r;
                int col = bn + wn * 64 + j * 16 + ln;
                C[(size_t)row * N + col] = f2bf(acc[i][j][r]);
            }
}

// ---------- GEMM 128x64 tiles (output proj), dbuf + bijective swizzle ----------
__global__ __launch_bounds__(256) void k_gemm_n64(const unsigned short* __restrict__ A,
                                                  const unsigned short* __restrict__ Bt,
                                                  float* __restrict__ C,
                                                  int N, int K) {
    __shared__ alignas(16) unsigned short As[2][128 * 32];
    __shared__ alignas(16) unsigned short Bs[2][64 * 32];
    const int t = threadIdx.x;
    const int lane = t & 63, wv = t >> 6;
    const int ln = lane & 15, quad = lane >> 4;
    const int bm = blockIdx.y * 128, bn = blockIdx.x * 64;

    floatx4 acc[2][4] = {};

    const int srow = t >> 2;
    const int sc = (t & 3) ^ ((srow >> 1) & 3);
    const unsigned short* ga0 = A + (size_t)(bm + srow) * K + sc * 8;
    const unsigned short* ga1 = ga0 + (size_t)64 * K;
    const unsigned short* gb0 = Bt + (size_t)(bn + srow) * K + sc * 8;

    gll16(ga0, &As[0][wv * 512]);
    gll16(ga1, &As[0][2048 + wv * 512]);
    gll16(gb0, &Bs[0][wv * 512]);

    const int sw = (ln >> 1) & 3;
    int cur = 0;
    for (int k0 = 0; k0 < K; k0 += 32, cur ^= 1) {
        __syncthreads();
        const int nk = k0 + 32;
        if (nk < K) {
            gll16(ga0 + nk, &As[cur ^ 1][wv * 512]);
            gll16(ga1 + nk, &As[cur ^ 1][2048 + wv * 512]);
            gll16(gb0 + nk, &Bs[cur ^ 1][wv * 512]);
        }
        shortx8 af[2], bfr[4];
#pragma unroll
        for (int i = 0; i < 2; ++i)
            af[i] = *(const shortx8*)(&As[cur][(wv * 32 + i * 16 + ln) * 32 + ((quad ^ sw) * 8)]);
#pragma unroll
        for (int j = 0; j < 4; ++j)
            bfr[j] = *(const shortx8*)(&Bs[cur][(j * 16 + ln) * 32 + ((quad ^ sw) * 8)]);
#pragma unroll
        for (int i = 0; i < 2; ++i)
#pragma unroll
            for (int j = 0; j < 4; ++j)
                acc[i][j] = __builtin_amdgcn_mfma_f32_16x16x32_bf16(af[i], bfr[j], acc[i][j], 0, 0, 0);
    }

#pragma unroll
    for (int i = 0; i < 2; ++i)
#pragma unroll
        for (int j = 0; j < 4; ++j)
#pragma unroll
            for (int r = 0; r < 4; ++r) {
                int row = bm + wv * 32 + i * 16 + quad * 4 + r;
                int col = bn + j * 16 + ln;
                C[(size_t)row * N + col] = acc[i][j][r];
            }
}

// ---------- fused causal attention + Hadamard: key-partitioned waves ----------
// 64-q tile, 64-key tiles. Wave w owns key sub-block jk=w (16 keys) and computes
// S^T/PV for ALL 64 q (aq[4][2] B-frags in regs). Per-wave-iter LDS: 2 b128 (kf)
// + 4 b64 (krf, shared across q-blocks) — ~5x less than q-partitioned scheme,
// and no wave-redundant reads. Partial O^T accumulators are tree-reduced through
// LDS (fp32) once per block. Grid 1-D 1024, XCD-pinned: bh = (flat&7)*4 +
// ((flat>>3)&3) so each bh's 512 KB K/KR set stays in ONE XCD's L2.
__global__ __launch_bounds__(256, 2) void k_attn(const unsigned short* __restrict__ qcat,
                                                 const unsigned short* __restrict__ krT,
                                                 unsigned short* __restrict__ ar) {
    __shared__ alignas(16) unsigned short Kl[2][64 * 64];  // [m][d] swizzled
    __shared__ alignas(16) unsigned short Rl[2][64 * 64];  // [d][m] swizzled
    __shared__ float Ls[4][4][16];                         // lsum partials [w][qc][ln]

    const int t = threadIdx.x;
    const int lane = t & 63, w = t >> 6;
    const int ln = lane & 15, quad = lane >> 4;
    const int flat = blockIdx.x;
    const int bh = (flat & 7) * 4 + ((flat >> 3) & 3);     // XCD-pinned head
    const int qts = flat >> 5;                             // 0..31
    const int qt = (qts & 1) ? 31 - (qts >> 1) : (qts >> 1);
    const int b = bh >> 4, h = bh & 15;
    const int l0 = qt * 64;
    const size_t baserow = (size_t)b * 2048;

    // Q B-frags for ALL 4 q-blocks: col q = qc*16+ln, k(d) = quad*8+i (+32)
    shortx8 aq[4][2];
#pragma unroll
    for (int qc = 0; qc < 4; ++qc) {
        const unsigned short* qp =
            qcat + (baserow + l0 + qc * 16 + ln) * 4096 + h * 64 + quad * 8;
        aq[qc][0] = *(const shortx8*)(qp);
        aq[qc][1] = *(const shortx8*)(qp + 32);
    }

    floatx4 acc_o[4][4] = {};   // [qc][jd] partial over THIS wave's keys
    float lsum[4] = {0.f, 0.f, 0.f, 0.f};

    const int srow = t >> 3;
    const int sc = (t & 7) ^ (srow & 7);
    const unsigned short* gK = qcat + (baserow + srow) * 4096 + 1024 + h * 64 + sc * 8;
    const unsigned short* gR = krT + ((size_t)bh * 64 + srow) * 2048 + sc * 8;

    auto stage = [&](int kt, int buf) {
        gll16(gK + (size_t)(kt * 64) * 4096,      &Kl[buf][w * 512]);
        gll16(gK + (size_t)(kt * 64 + 32) * 4096, &Kl[buf][2048 + w * 512]);
        gll16(gR + kt * 64,                       &Rl[buf][w * 512]);
        gll16(gR + (size_t)32 * 2048 + kt * 64,   &Rl[buf][2048 + w * 512]);
    };

    stage(0, 0);
    const int swz = ln & 7;          // read-side swizzle key (rows stride 16: &7 == ln&7)
    const int krow = (w * 16 + ln) * 64;
    const int cmw = w * 2 + (quad >> 1);
    int cur = 0;
    for (int kt = 0; kt <= qt; ++kt, cur ^= 1) {
        __syncthreads();             // drains DMA; prev iter's LDS reads done
        if (kt < qt) stage(kt + 1, cur ^ 1);
        const unsigned short* Kc = Kl[cur];
        const unsigned short* Rc = Rl[cur];
        const bool diag = (kt == qt);

        // this wave's K fragments (keys w*16 + quad*4+r after MFMA)
        shortx8 kf0 = *(const shortx8*)(Kc + krow + ((quad ^ swz) * 8));
        shortx8 kf1 = *(const shortx8*)(Kc + krow + (((4 + quad) ^ swz) * 8));
        // this wave's KR A-frags, shared across all q-blocks
        shortx4 krf[4];
#pragma unroll
        for (int jd = 0; jd < 4; ++jd)
            krf[jd] = *(const shortx4*)(Rc + (jd * 16 + ln) * 64 +
                                        ((cmw ^ swz) * 8) + (quad & 1) * 4);

        const int keyb = kt * 64 + w * 16 + quad * 4;   // global key (+r)
        shortx4 pk[4];
#pragma unroll
        for (int qc = 0; qc < 4; ++qc) {
            floatx4 z = {0.f, 0.f, 0.f, 0.f};
            z = __builtin_amdgcn_mfma_f32_16x16x32_bf16(kf0, aq[qc][0], z, 0, 0, 0);
            z = __builtin_amdgcn_mfma_f32_16x16x32_bf16(kf1, aq[qc][1], z, 0, 0, 0);
            float e0 = exp2fast(z[0]);
            float e1 = exp2fast(z[1]);
            float e2 = exp2fast(z[2]);
            float e3 = exp2fast(z[3]);
            if (diag) {
                const int q = l0 + qc * 16 + ln;
                e0 = (keyb + 0 > q) ? 0.f : e0;
                e1 = (keyb + 1 > q) ? 0.f : e1;
                e2 = (keyb + 2 > q) ? 0.f : e2;
                e3 = (keyb + 3 > q) ? 0.f : e3;
            }
            lsum[qc] += (e0 + e1) + (e2 + e3);
            struct U2 { unsigned a, b; } u{pkbf(e0, e1), pkbf(e2, e3)};
            pk[qc] = __builtin_bit_cast(shortx4, u);
        }

#pragma unroll
        for (int qc = 0; qc < 4; ++qc)
#pragma unroll
            for (int jd = 0; jd < 4; ++jd)
                acc_o[qc][jd] = mfma16(krf[jd], pk[qc], acc_o[qc][jd]);
    }

    // lsum: reduce over quads inside the wave, publish per-wave partial
#pragma unroll
    for (int qc = 0; qc < 4; ++qc) {
        float s = lsum[qc];
        s += __shfl_xor(s, 16);
        s += __shfl_xor(s, 32);
        lsum[qc] = s;
    }
    if (lane < 16) {
#pragma unroll
        for (int qc = 0; qc < 4; ++qc) Ls[w][qc][lane] = lsum[qc];
    }

    // cross-wave O^T reduction through LDS (fp32), tree: (2,3)->(0,1), 1->0
    __syncthreads();                  // loop reads done; Kl/Rl reusable; Ls visible
    float* redA = (float*)&Kl[0][0];  // 4096 floats
    float* redB = (float*)&Rl[0][0];  // 4096 floats
    if (w >= 2) {
        float* dst = (w == 2) ? redA : redB;
#pragma unroll
        for (int qc = 0; qc < 4; ++qc)
#pragma unroll
            for (int jd = 0; jd < 4; ++jd)
                *(floatx4*)(dst + ((qc * 4 + jd) * 64 + lane) * 4) = acc_o[qc][jd];
    }
    __syncthreads();
    if (w < 2) {
        const float* src = (w == 0) ? redA : redB;
#pragma unroll
        for (int qc = 0; qc < 4; ++qc)
#pragma unroll
            for (int jd = 0; jd < 4; ++jd)
                acc_o[qc][jd] += *(const floatx4*)(src + ((qc * 4 + jd) * 64 + lane) * 4);
    }
    __syncthreads();
    if (w == 1) {
#pragma unroll
        for (int qc = 0; qc < 4; ++qc)
#pragma unroll
            for (int jd = 0; jd < 4; ++jd)
                *(floatx4*)(redA + ((qc * 4 + jd) * 64 + lane) * 4) = acc_o[qc][jd];
    }
    __syncthreads();
    if (w == 0) {
        float inv[4];
#pragma unroll
        for (int qc = 0; qc < 4; ++qc)
            inv[qc] = 1.0f / (Ls[0][qc][ln] + Ls[1][qc][ln] + Ls[2][qc][ln] + Ls[3][qc][ln]);
#pragma unroll
        for (int qc = 0; qc < 4; ++qc) {
            const int q = l0 + qc * 16 + ln;
            const unsigned short* qr = qcat + (baserow + q) * 4096 + 2048 + h * 64;
            unsigned short* arow = ar + (baserow + q) * 1024 + h * 64;
#pragma unroll
            for (int jd = 0; jd < 4; ++jd) {
                floatx4 a = acc_o[qc][jd];
                a += *(const floatx4*)(redA + ((qc * 4 + jd) * 64 + lane) * 4);
                const int d0 = jd * 16 + quad * 4;
                shortx4 qv = *(const shortx4*)(qr + d0);
                shortx4 o;
#pragma unroll
                for (int r = 0; r < 4; ++r)
                    o[r] = (short)f2bf(a[r] * inv[qc] * bf2f((unsigned short)qv[r]));
                *(shortx4*)(arow + d0) = o;
            }
        }
    }
}

extern "C" void kernel_launch(void* const* d_in, const int* in_sizes, int n_in,
                              void* d_out, int out_size, void* d_ws, size_t ws_size,
                              hipStream_t stream) {
    const float* x   = (const float*)d_in[0];
    const float* wq  = (const float*)d_in[1];
    const float* wk  = (const float*)d_in[2];
    const float* wqr = (const float*)d_in[3];
    const float* wkr = (const float*)d_in[4];
    const float* wo  = (const float*)d_in[5];
    float* out = (float*)d_out;

    unsigned short* xb    = (unsigned short*)d_ws;
    unsigned short* wcatT = xb + (size_t)4096 * 1024;
    unsigned short* qcat  = wcatT + (size_t)4096 * 1024;
    unsigned short* wotT  = qcat + (size_t)4096 * 4096;
    unsigned short* krT   = wcatT;   // wcatT dead after proj GEMM
    unsigned short* arb   = xb;      // xb dead after proj GEMM

    k_cvt_x<<<4096, 256, 0, stream>>>(x, xb);
    k_cvt_w5<<<dim3(16, 16, 5), 256, 0, stream>>>(wq, wk, wqr, wkr, wo, wcatT, wotT);
    k_gemm_bt<<<dim3(32, 32), 256, 0, stream>>>(xb, wcatT, qcat, 4096, 1024);
    k_trans<<<dim3(32, 32), 256, 0, stream>>>(qcat, krT);
    k_attn<<<1024, 256, 0, stream>>>(qcat, krT, arb);
    k_gemm_n64<<<dim3(16, 32), 256, 0, stream>>>(arb, wotT, out, 1024, 1024);
}